// Round 1
// baseline (167.842 us; speedup 1.0000x reference)
//
#include <hip/hip_runtime.h>
#include <hip/hip_bf16.h>

// Problem config (mirrors reference)
#define BB 8
#define NN 4096
#define MM 1024
#define CC 10

// Tiling: 256-thread blocks = 4 waves; each wave owns ROWS_PER_WAVE consecutive
// n-rows and computes the full M=1024 columns for each row.
// Lane l handles m = l + 64*i, i = 0..15  -> unit-stride coalesced stores.
#define ROWS_PER_WAVE 8
#define ROWS_PER_BLOCK 32              // 4 waves * 8 rows
#define BLOCKS_PER_BATCH (NN / ROWS_PER_BLOCK)   // 128

__global__ __launch_bounds__(256, 2)
void transfusion_cost_kernel(const float* __restrict__ bboxes,      // [B,N,7]
                             const float* __restrict__ gt_bboxes,   // [B,M,7]
                             const float* __restrict__ cls_pred,    // [B,N,C]
                             const int*   __restrict__ gt_labels,   // [B,M]
                             float* __restrict__ out)               // [B,N,M]
{
    const int tid  = threadIdx.x;
    const int lane = tid & 63;
    const int wave = tid >> 6;

    const int bk = blockIdx.x;
    const int b  = bk / BLOCKS_PER_BATCH;
    const int n0 = (bk % BLOCKS_PER_BATCH) * ROWS_PER_BLOCK + wave * ROWS_PER_WAVE;

    const float* gtb = gt_bboxes + (size_t)b * MM * 7;
    const int*   gtl = gt_labels + (size_t)b * MM;

    // ---- per-lane gt data for its 16 m-slots (same for every row -> registers) ----
    // Fold REG_W/range into the xy normalization: reg = |axs-bxs| + |ays-bys|
    const float SCL = 0.25f / 108.0f;

    float gx1[16], gy1[16], gx2[16], gy2[16];
    float areaB[16], bxs[16], bys[16];
    int   lbl[16];

#pragma unroll
    for (int i = 0; i < 16; ++i) {
        const int m = lane + 64 * i;
        const float* g = gtb + m * 7;
        const float x  = g[0];
        const float y  = g[1];
        const float dx = g[3];
        const float dy = g[4];
        const float x1 = x - 0.5f * dx, x2 = x + 0.5f * dx;
        const float y1 = y - 0.5f * dy, y2 = y + 0.5f * dy;
        gx1[i] = x1; gy1[i] = y1; gx2[i] = x2; gy2[i] = y2;
        areaB[i] = fmaxf(x2 - x1, 0.0f) * fmaxf(y2 - y1, 0.0f);
        bxs[i] = (x + 54.0f) * SCL;
        bys[i] = (y + 54.0f) * SCL;
        lbl[i] = gtl[m];
    }

    // ---- loop over this wave's rows ----
    for (int r = 0; r < ROWS_PER_WAVE; ++r) {
        const int n = n0 + r;

        const float* a = bboxes + ((size_t)b * NN + n) * 7;
        const float ax  = a[0];
        const float ay  = a[1];
        const float adx = a[3];
        const float ady = a[4];
        const float xa1 = ax - 0.5f * adx, xa2 = ax + 0.5f * adx;
        const float ya1 = ay - 0.5f * ady, ya2 = ay + 0.5f * ady;
        const float areaA = fmaxf(xa2 - xa1, 0.0f) * fmaxf(ya2 - ya1, 0.0f);
        const float axs = (ax + 54.0f) * SCL;
        const float ays = (ay + 54.0f) * SCL;

        // focal diff for channel == lane (only lanes 0..9 meaningful)
        const int c = (lane < CC) ? lane : 0;
        const float logit = cls_pred[((size_t)b * NN + n) * CC + c];
        const float p   = 1.0f / (1.0f + expf(-logit));
        const float omp = 1.0f - p;
        const float pos = -logf(p   + 1e-12f) * 0.25f * omp * omp;
        const float neg = -logf(omp + 1e-12f) * 0.75f * p * p;
        const float dval = (pos - neg) * 0.15f;

        float* orow = out + ((size_t)b * NN + n) * MM;

#pragma unroll
        for (int i = 0; i < 16; ++i) {
            const int m = lane + 64 * i;

            const float ix1 = fmaxf(xa1, gx1[i]);
            const float iy1 = fmaxf(ya1, gy1[i]);
            const float ix2 = fminf(xa2, gx2[i]);
            const float iy2 = fminf(ya2, gy2[i]);
            const float iw  = fmaxf(ix2 - ix1, 0.0f);
            const float ih  = fmaxf(iy2 - iy1, 0.0f);
            const float inter = iw * ih;
            const float uni   = areaA + areaB[i] - inter;
            const float iou   = inter / fmaxf(uni, 1e-6f);

            const float cls = __shfl(dval, lbl[i], 64);
            const float reg = fabsf(axs - bxs[i]) + fabsf(ays - bys[i]);

            orow[m] = cls + reg - 0.25f * iou;
        }
    }
}

extern "C" void kernel_launch(void* const* d_in, const int* in_sizes, int n_in,
                              void* d_out, int out_size, void* d_ws, size_t ws_size,
                              hipStream_t stream) {
    const float* bboxes    = (const float*)d_in[0];
    const float* gt_bboxes = (const float*)d_in[1];
    const float* cls_pred  = (const float*)d_in[2];
    const int*   gt_labels = (const int*)d_in[3];
    float* out = (float*)d_out;

    const int grid = BB * BLOCKS_PER_BATCH;   // 1024 blocks
    transfusion_cost_kernel<<<grid, 256, 0, stream>>>(bboxes, gt_bboxes, cls_pred,
                                                      gt_labels, out);
}